// Round 5
// baseline (303.727 us; speedup 1.0000x reference)
//
#include <hip/hip_runtime.h>

#define EPSF 1e-8f
#define CCH 128
#define HWSZ 65536
#define NPIX 262144
#define KTOP 13107
#define LN2F 0.6931471805599453f

// ws layout (32-bit words)
#define WS_SUM    0      // [512] f32: sumP[128], sumsqP[128], sumT[128], sumsqT[128]
#define WS_CST    512    // [512] f32: float4 per channel c: (m_p, i_p, m_t, i_t)
#define WS_WGT    1024   // [9] f32 softmax weights
#define WS_MINKEY 1040
#define WS_MAXKEY 1041
#define WS_BSTAR  1042
#define WS_CNTAB  1043
#define WS_LO2    1044
#define WS_W2     1045
#define WS_K2     1046
#define WS_SUMAB  1048
#define WS_H1     1056   // [4096] u32
#define WS_H2C    5152   // [4096] u32
#define WS_H2S    9248   // [4096] f32
#define WS_TOTAL  13344

__device__ __forceinline__ unsigned fkey(float f){
  unsigned u = __float_as_uint(f);
  return (u & 0x80000000u) ? ~u : (u | 0x80000000u);
}
__device__ __forceinline__ float funkey(unsigned k){
  unsigned u = (k & 0x80000000u) ? (k & 0x7fffffffu) : ~k;
  return __uint_as_float(u);
}

__global__ __launch_bounds__(256) void initWs(unsigned* __restrict__ wsu){
  int idx = blockIdx.x*256 + threadIdx.x;
  if (idx < WS_TOTAL) wsu[idx] = (idx == WS_MINKEY) ? 0xFFFFFFFFu : 0u;
}

// per-channel sums over (B,H,W) for both tensors
__global__ __launch_bounds__(512) void bnSumKernel(const float* __restrict__ rec,
                                                   const float* __restrict__ tgt,
                                                   float* __restrict__ wsf){
  int blk = blockIdx.x;            // 0..1023: tensor(2) x b(4) x c(128)
  int tensor = blk >> 9;
  int rem = blk & 511;
  int c = rem & 127;
  int b = rem >> 7;
  const float* src = (tensor==0 ? rec : tgt) + ((size_t)(b*CCH + c))*HWSZ;
  const float4* src4 = (const float4*)src;
  float s=0.f, q=0.f;
  #pragma unroll 4
  for (int j=threadIdx.x; j<HWSZ/4; j+=512){
    float4 v = src4[j];
    s += v.x+v.y+v.z+v.w;
    q += v.x*v.x + v.y*v.y + v.z*v.z + v.w*v.w;
  }
  for (int off=1; off<64; off<<=1){ s += __shfl_xor(s,off); q += __shfl_xor(q,off); }
  __shared__ float ls[8], lq[8];
  int wid = threadIdx.x >> 6;
  if ((threadIdx.x & 63)==0){ ls[wid]=s; lq[wid]=q; }
  __syncthreads();
  if (threadIdx.x==0){
    float S=0,Q=0;
    for (int i=0;i<8;i++){ S+=ls[i]; Q+=lq[i]; }
    atomicAdd(&wsf[tensor*256 + c], S);
    atomicAdd(&wsf[tensor*256 + 128 + c], Q);
  }
}

// bn mean/inv-std per channel (both tensors) + softmax weights
__global__ __launch_bounds__(256) void finalizeKernel(const float* __restrict__ lw,
                                                      float* __restrict__ wsf){
  int tid = threadIdx.x;
  {
    int tensor = tid >> 7;
    int c = tid & 127;
    float S = wsf[tensor*256 + c];
    float Q = wsf[tensor*256 + 128 + c];
    const float N = 262144.f;
    float mean = S / N;
    float var = fmaxf((Q - S*S/N) / (N - 1.f), 0.f);
    float inv = 1.f/(sqrtf(var)+EPSF);
    wsf[WS_CST + c*4 + tensor*2 + 0] = mean;
    wsf[WS_CST + c*4 + tensor*2 + 1] = inv;
  }
  if (tid==0){
    float m = -1e30f;
    for (int i=0;i<9;i++) m = fmaxf(m, lw[i]);
    float e[9], sum=0.f;
    for (int i=0;i<9;i++){ e[i]=expf(lw[i]-m); sum+=e[i]; }
    for (int i=0;i<9;i++) wsf[WS_WGT+i] = e[i]/sum;
  }
}

// main kernel: block = 64 pixels. Stage full tile (128 ch x 64 pix x 2 tensors,
// 64KB) into LDS with 16 coalesced float4 loads/thread; pass1 moments and SID
// pass both read from LDS. Thread = (pixel p = tid&63, channel-group cg=tid>>6).
__global__ __launch_bounds__(256, 2) void mainKernel(const float* __restrict__ rec,
                                                     const float* __restrict__ tgt,
                                                     const float* __restrict__ wsf,
                                                     unsigned* __restrict__ wsu,
                                                     float* __restrict__ errMap){
  __shared__ float tile[256*64];     // rows 0..127: rec ch c; 128..255: tgt ch c
  __shared__ float red[8][4][64];    // reused 3x
  __shared__ float4 cstLds[128];
  __shared__ float wgtLds[12];

  int tid = threadIdx.x;
  int P0 = blockIdx.x*64;
  int b = P0 >> 16;
  int hw0 = P0 & (HWSZ-1);
  const float* base0 = rec + ((size_t)b*CCH)*HWSZ + hw0;
  const float* base1 = tgt + ((size_t)b*CCH)*HWSZ + hw0;

  if (tid < 128) cstLds[tid] = ((const float4*)(wsf + WS_CST))[tid];
  if (tid < 9)  wgtLds[tid] = wsf[WS_WGT + tid];

  int quad = tid & 15;          // pixel quad (4 pixels)
  int rowsel = tid >> 4;        // 0..15
  float4 v[16];
  #pragma unroll
  for (int k=0;k<16;k++){
    int c = (k&7)*16 + rowsel;
    const float* src = ((k<8)? base0 : base1) + ((size_t)c*HWSZ) + quad*4;
    v[k] = *(const float4*)src;
  }
  #pragma unroll
  for (int k=0;k<16;k++){
    int row = k*16 + rowsel;
    *(float4*)&tile[row*64 + quad*4] = v[k];
  }
  __syncthreads();

  int p = tid & 63, cg = tid >> 6;
  float psum=0,psumsq=0,tsum=0,tsumsq=0,ptsum=0;
  float pmin=3.4e38f,pmax=-3.4e38f,tmin=3.4e38f,tmax=-3.4e38f;
  float bS1=0,bS11=0,bS2=0,bS22=0,bS12=0,bMp=3.4e38f,bMt=3.4e38f;

  #pragma unroll 8
  for (int i=0;i<32;i++){
    int c = cg*32 + i;
    float pv = tile[c*64 + p];
    float tv = tile[(128+c)*64 + p];
    float4 c4 = cstLds[c];
    psum+=pv; psumsq=fmaf(pv,pv,psumsq);
    tsum+=tv; tsumsq=fmaf(tv,tv,tsumsq);
    ptsum=fmaf(pv,tv,ptsum);
    pmin=fminf(pmin,pv); pmax=fmaxf(pmax,pv);
    tmin=fminf(tmin,tv); tmax=fmaxf(tmax,tv);
    float bp = fmaf(pv, c4.y, -c4.x*c4.y);
    float bt = fmaf(tv, c4.w, -c4.z*c4.w);
    bS1+=bp; bS11=fmaf(bp,bp,bS11);
    bS2+=bt; bS22=fmaf(bt,bt,bS22);
    bS12=fmaf(bp,bt,bS12);
    bMp=fminf(bMp,bp); bMt=fminf(bMt,bt);
  }

  #define CS(s) (red[s][0][p]+red[s][1][p]+red[s][2][p]+red[s][3][p])
  #define CN(s) fminf(fminf(red[s][0][p],red[s][1][p]),fminf(red[s][2][p],red[s][3][p]))
  #define CX(s) fmaxf(fmaxf(red[s][0][p],red[s][1][p]),fmaxf(red[s][2][p],red[s][3][p]))

  // combine round A
  red[0][cg][p]=psum; red[1][cg][p]=psumsq; red[2][cg][p]=tsum; red[3][cg][p]=tsumsq;
  red[4][cg][p]=ptsum; red[5][cg][p]=pmin; red[6][cg][p]=pmax; red[7][cg][p]=tmin;
  __syncthreads();
  psum=CS(0); psumsq=CS(1); tsum=CS(2); tsumsq=CS(3); ptsum=CS(4);
  pmin=CN(5); pmax=CX(6); tmin=CN(7);
  __syncthreads();
  // combine round B
  red[0][cg][p]=tmax; red[1][cg][p]=bS1; red[2][cg][p]=bS11; red[3][cg][p]=bS2;
  red[4][cg][p]=bS22; red[5][cg][p]=bS12; red[6][cg][p]=bMp; red[7][cg][p]=bMt;
  __syncthreads();
  tmax=CX(0); bS1=CS(1); bS11=CS(2); bS2=CS(3); bS22=CS(4); bS12=CS(5);
  bMp=CN(6); bMt=CN(7);
  __syncthreads();   // red free for SID partials

  // SID pass: every thread has the full-channel stats; constants per pixel
  float smm_p = 1.f/(pmax-pmin+EPSF);
  float smm_t = 1.f/(tmax-tmin+EPSF);
  float dp = fmaf(psum - 128.f*pmin, smm_p, EPSF);
  float fp = smm_p/dp;  float Bp = pmin*fp;
  float dt = fmaf(tsum - 128.f*tmin, smm_t, EPSF);
  float ft = smm_t/dt;  float Bt = tmin*ft;
  float fbp = 1.f/((bS1 - 128.f*bMp) + EPSF); float Bbp = bMp*fbp;
  float fbt = 1.f/((bS2 - 128.f*bMt) + EPSF); float Bbt = bMt*fbt;

  float sid_mm=0.f, sid_bn=0.f;
  #pragma unroll 8
  for (int i=0;i<32;i++){
    int c = cg*32 + i;
    float pv = tile[c*64 + p];
    float tv = tile[(128+c)*64 + p];
    float pp = fmaxf(fmaf(pv,fp,-Bp), EPSF);
    float tp = fmaxf(fmaf(tv,ft,-Bt), EPSF);
    sid_mm = fmaf(pp-tp, __log2f(pp)-__log2f(tp), sid_mm);
    float4 c4 = cstLds[c];
    float bp = fmaf(pv, c4.y, -c4.x*c4.y);
    float bt = fmaf(tv, c4.w, -c4.z*c4.w);
    float qp = fmaxf(fmaf(bp,fbp,-Bbp), EPSF);
    float qt = fmaxf(fmaf(bt,fbt,-Bbt), EPSF);
    sid_bn = fmaf(qp-qt, __log2f(qp)-__log2f(qt), sid_bn);
  }
  red[0][cg][p]=sid_mm; red[1][cg][p]=sid_bn;
  __syncthreads();

  if (cg==0){
    sid_mm = CS(0)*LN2F;
    sid_bn = CS(1)*LN2F;

    const float Ci = 1.0f/128.0f;
    float mean_p = psum*Ci, mean_t = tsum*Ci;
    float var_p = fmaxf((psumsq - psum*psum*Ci)*(1.f/127.f), 0.f);
    float var_t = fmaxf((tsumsq - tsum*tsum*Ci)*(1.f/127.f), 0.f);
    float zi_p = 1.f/(sqrtf(var_p)+EPSF);
    float zi_t = 1.f/(sqrtf(var_t)+EPSF);

    auto metrics = [](float S1,float S11,float S2,float S22,float S12,
                      float& sam,float& pear){
      float npn = fmaxf(sqrtf(fmaxf(S11,0.f)), EPSF);
      float ntn = fmaxf(sqrtf(fmaxf(S22,0.f)), EPSF);
      sam = 1.f - S12/(npn*ntn);
      const float ci = 1.0f/128.0f;
      float cov = S12 - S1*S2*ci;
      float vp = fmaxf(S11 - S1*S1*ci, 0.f);
      float vt = fmaxf(S22 - S2*S2*ci, 0.f);
      pear = 1.f - cov/(sqrtf(vp+EPSF)*sqrtf(vt+EPSF));
    };
    auto affine = [&](float ap,float sp,float at,float st,float& sam,float& pear){
      float S1 = (psum - 128.f*ap)*sp;
      float S11 = (psumsq - 2.f*ap*psum + 128.f*ap*ap)*sp*sp;
      float S2 = (tsum - 128.f*at)*st;
      float S22 = (tsumsq - 2.f*at*tsum + 128.f*at*at)*st*st;
      float S12 = (ptsum - at*psum - ap*tsum + 128.f*ap*at)*sp*st;
      metrics(S1,S11,S2,S22,S12,sam,pear);
    };

    float sam_mm,pear_mm,sam_z,pear_z,sam_bn,pear_bn;
    affine(pmin,smm_p,tmin,smm_t,sam_mm,pear_mm);
    affine(mean_p,zi_p,mean_t,zi_t,sam_z,pear_z);
    metrics(bS1,bS11,bS2,bS22,bS12,sam_bn,pear_bn);

    float err = wgtLds[0]*sam_mm + wgtLds[1]*pear_mm + (wgtLds[2]+wgtLds[5])*sid_mm
              + wgtLds[3]*sam_z  + wgtLds[4]*pear_z
              + wgtLds[6]*sam_bn + wgtLds[7]*pear_bn + wgtLds[8]*sid_bn;
    errMap[P0 + p] = err;

    float emin = err, emax = err;
    #pragma unroll
    for (int off=1; off<64; off<<=1){
      emin = fminf(emin, __shfl_xor(emin,off));
      emax = fmaxf(emax, __shfl_xor(emax,off));
    }
    if (p==0){
      atomicMin(&wsu[WS_MINKEY], fkey(emin));
      atomicMax(&wsu[WS_MAXKEY], fkey(emax));
    }
  }
  #undef CS
  #undef CN
  #undef CX
}

__global__ __launch_bounds__(256) void hist1Kernel(const float* __restrict__ err,
                                                   unsigned* __restrict__ wsu){
  __shared__ unsigned h[4096];
  int tid = threadIdx.x;
  for (int i=tid;i<4096;i+=256) h[i]=0u;
  __syncthreads();
  float lo = funkey(wsu[WS_MINKEY]);
  float hi = funkey(wsu[WS_MAXKEY]);
  float invw = 4096.f / fmaxf(hi-lo, 1e-30f);
  int base = blockIdx.x*2048 + tid;
  for (int j=0;j<8;j++){
    float v = err[base + j*256];
    int idx = (int)fminf(fmaxf((v-lo)*invw, 0.f), 4095.f);
    atomicAdd(&h[idx], 1u);
  }
  __syncthreads();
  for (int i=tid;i<4096;i+=256){ unsigned c=h[i]; if (c) atomicAdd(&wsu[WS_H1+i], c); }
}

__global__ __launch_bounds__(256) void scan1Kernel(float* __restrict__ wsf,
                                                   unsigned* __restrict__ wsu){
  __shared__ unsigned counts[4096];
  __shared__ unsigned s[256];
  int tid = threadIdx.x;
  for (int i=tid;i<4096;i+=256) counts[i]=wsu[WS_H1+i];
  __syncthreads();
  unsigned part=0;
  for (int j=0;j<16;j++) part += counts[tid*16+j];
  s[tid]=part; __syncthreads();
  for (int off=1; off<256; off<<=1){
    unsigned v = (tid+off<256)? s[tid+off] : 0u;
    __syncthreads();
    s[tid] += v;
    __syncthreads();
  }
  float lo = funkey(wsu[WS_MINKEY]);
  float hi = funkey(wsu[WS_MAXKEY]);
  float w1 = fmaxf(hi-lo, 1e-30f) * (1.f/4096.f);
  unsigned cum = (tid<255)? s[tid+1] : 0u;
  for (int j=15;j>=0;j--){
    int bin = tid*16+j;
    unsigned cn = cum + counts[bin];
    if (cum < (unsigned)KTOP && cn >= (unsigned)KTOP){
      wsu[WS_BSTAR] = (unsigned)bin;
      wsu[WS_CNTAB] = cum;
      wsu[WS_K2]    = (unsigned)KTOP - cum;
      wsf[WS_LO2]   = lo + (float)bin*w1;
      wsf[WS_W2]    = w1*(1.f/4096.f);
    }
    cum = cn;
  }
}

__global__ __launch_bounds__(256) void hist2Kernel(const float* __restrict__ err,
                                                   float* __restrict__ wsf,
                                                   unsigned* __restrict__ wsu){
  __shared__ unsigned h2[4096];
  __shared__ float s2[4096];
  __shared__ float ls[4];
  int tid = threadIdx.x;
  for (int i=tid;i<4096;i+=256){ h2[i]=0u; s2[i]=0.f; }
  __syncthreads();
  float lo = funkey(wsu[WS_MINKEY]);
  float hi = funkey(wsu[WS_MAXKEY]);
  float invw = 4096.f / fmaxf(hi-lo, 1e-30f);
  int bstar = (int)wsu[WS_BSTAR];
  float lo2 = wsf[WS_LO2];
  float w2  = wsf[WS_W2];
  float invw2 = 1.f / w2;
  float mySum = 0.f;
  int base = blockIdx.x*2048 + tid;
  for (int j=0;j<8;j++){
    float v = err[base + j*256];
    int idx = (int)fminf(fmaxf((v-lo)*invw, 0.f), 4095.f);
    if (idx > bstar){
      mySum += v;
    } else if (idx == bstar){
      int i2 = (int)fminf(fmaxf((v-lo2)*invw2, 0.f), 4095.f);
      atomicAdd(&h2[i2], 1u);
      atomicAdd(&s2[i2], v);
    }
  }
  for (int off=1; off<64; off<<=1) mySum += __shfl_xor(mySum, off);
  if ((tid&63)==0) ls[tid>>6] = mySum;
  __syncthreads();
  if (tid==0) atomicAdd(&wsf[WS_SUMAB], ls[0]+ls[1]+ls[2]+ls[3]);
  for (int i=tid;i<4096;i+=256){
    unsigned c = h2[i]; if (c) atomicAdd(&wsu[WS_H2C+i], c);
    float sv = s2[i];   if (sv != 0.f) atomicAdd(&wsf[WS_H2S+i], sv);
  }
}

__global__ __launch_bounds__(256) void scan2Kernel(float* __restrict__ wsf,
                                                   unsigned* __restrict__ wsu,
                                                   float* __restrict__ out){
  __shared__ unsigned cnt[4096];
  __shared__ float sm[4096];
  __shared__ unsigned sC[256];
  __shared__ float sS[256];
  int tid = threadIdx.x;
  for (int i=tid;i<4096;i+=256){ cnt[i]=wsu[WS_H2C+i]; sm[i]=wsf[WS_H2S+i]; }
  __syncthreads();
  unsigned pc=0; float ps=0.f;
  for (int j=0;j<16;j++){ pc+=cnt[tid*16+j]; ps+=sm[tid*16+j]; }
  sC[tid]=pc; sS[tid]=ps; __syncthreads();
  for (int off=1; off<256; off<<=1){
    unsigned vc = (tid+off<256)? sC[tid+off] : 0u;
    float vs    = (tid+off<256)? sS[tid+off] : 0.f;
    __syncthreads();
    sC[tid] += vc; sS[tid] += vs;
    __syncthreads();
  }
  unsigned k2 = wsu[WS_K2];
  float lo2 = wsf[WS_LO2], w2 = wsf[WS_W2];
  unsigned cum = (tid<255)? sC[tid+1] : 0u;
  float cums   = (tid<255)? sS[tid+1] : 0.f;
  for (int j=15;j>=0;j--){
    int bin = tid*16+j;
    unsigned cn = cum + cnt[bin];
    float sn = cums + sm[bin];
    if (cum < k2 && cn >= k2){
      float val = lo2 + ((float)bin + 0.5f)*w2;
      float total = wsf[WS_SUMAB] + cums + (float)(k2 - cum)*val;
      out[0] = total / (float)KTOP;
    }
    cum = cn; cums = sn;
  }
}

extern "C" void kernel_launch(void* const* d_in, const int* in_sizes, int n_in,
                              void* d_out, int out_size, void* d_ws, size_t ws_size,
                              hipStream_t stream){
  const float* rec = (const float*)d_in[0];
  const float* tgt = (const float*)d_in[1];
  const float* lw  = (const float*)d_in[2];
  float* out = (float*)d_out;
  float* wsf = (float*)d_ws;
  unsigned* wsu = (unsigned*)d_ws;

  hipLaunchKernelGGL(initWs, dim3((WS_TOTAL+255)/256), dim3(256), 0, stream, wsu);
  hipLaunchKernelGGL(bnSumKernel, dim3(1024), dim3(512), 0, stream, rec, tgt, wsf);
  hipLaunchKernelGGL(finalizeKernel, dim3(1), dim3(256), 0, stream, lw, wsf);
  hipLaunchKernelGGL(mainKernel, dim3(NPIX/64), dim3(256), 0, stream, rec, tgt, wsf, wsu, out+1);
  hipLaunchKernelGGL(hist1Kernel, dim3(128), dim3(256), 0, stream, out+1, wsu);
  hipLaunchKernelGGL(scan1Kernel, dim3(1), dim3(256), 0, stream, wsf, wsu);
  hipLaunchKernelGGL(hist2Kernel, dim3(128), dim3(256), 0, stream, out+1, wsf, wsu);
  hipLaunchKernelGGL(scan2Kernel, dim3(1), dim3(256), 0, stream, wsf, wsu, out);
}

// Round 6
// 198.702 us; speedup vs baseline: 1.5286x; 1.5286x over previous
//
#include <hip/hip_runtime.h>

#define EPSF 1e-8f
#define CCH 128
#define HWSZ 65536
#define NPIX 262144
#define KTOP 13107
#define LN2F 0.6931471805599453f

// ws layout (32-bit words)
#define WS_SUM    0      // [512] f32: sumP[128], sumsqP[128], sumT[128], sumsqT[128]
#define WS_CST    512    // [512] f32: float4 per channel c: (i_p, m_p*i_p, i_t, m_t*i_t)
#define WS_WGT    1024   // [9] f32 softmax weights
#define WS_MINKEY 1040
#define WS_MAXKEY 1041
#define WS_BSTAR  1042
#define WS_CNTAB  1043
#define WS_LO2    1044
#define WS_W2     1045
#define WS_K2     1046
#define WS_SUMAB  1048
#define WS_H1     1056   // [4096] u32
#define WS_H2C    5152   // [4096] u32
#define WS_H2S    9248   // [4096] f32
#define WS_TOTAL  13344

__device__ __forceinline__ unsigned fkey(float f){
  unsigned u = __float_as_uint(f);
  return (u & 0x80000000u) ? ~u : (u | 0x80000000u);
}
__device__ __forceinline__ float funkey(unsigned k){
  unsigned u = (k & 0x80000000u) ? (k & 0x7fffffffu) : ~k;
  return __uint_as_float(u);
}

__global__ __launch_bounds__(256) void initWs(unsigned* __restrict__ wsu){
  int idx = blockIdx.x*256 + threadIdx.x;
  if (idx < WS_TOTAL) wsu[idx] = (idx == WS_MINKEY) ? 0xFFFFFFFFu : 0u;
}

// per-channel sums over (B,H,W) for both tensors
__global__ __launch_bounds__(512) void bnSumKernel(const float* __restrict__ rec,
                                                   const float* __restrict__ tgt,
                                                   float* __restrict__ wsf){
  int blk = blockIdx.x;            // 0..1023: tensor(2) x b(4) x c(128)
  int tensor = blk >> 9;
  int rem = blk & 511;
  int c = rem & 127;
  int b = rem >> 7;
  const float* src = (tensor==0 ? rec : tgt) + ((size_t)(b*CCH + c))*HWSZ;
  const float4* src4 = (const float4*)src;
  float s=0.f, q=0.f;
  #pragma unroll 4
  for (int j=threadIdx.x; j<HWSZ/4; j+=512){
    float4 v = src4[j];
    s += v.x+v.y+v.z+v.w;
    q += v.x*v.x + v.y*v.y + v.z*v.z + v.w*v.w;
  }
  for (int off=1; off<64; off<<=1){ s += __shfl_xor(s,off); q += __shfl_xor(q,off); }
  __shared__ float ls[8], lq[8];
  int wid = threadIdx.x >> 6;
  if ((threadIdx.x & 63)==0){ ls[wid]=s; lq[wid]=q; }
  __syncthreads();
  if (threadIdx.x==0){
    float S=0,Q=0;
    for (int i=0;i<8;i++){ S+=ls[i]; Q+=lq[i]; }
    atomicAdd(&wsf[tensor*256 + c], S);
    atomicAdd(&wsf[tensor*256 + 128 + c], Q);
  }
}

// bn inv-std and mean*inv-std per channel (both tensors) + softmax weights
__global__ __launch_bounds__(256) void finalizeKernel(const float* __restrict__ lw,
                                                      float* __restrict__ wsf){
  int tid = threadIdx.x;
  {
    int tensor = tid >> 7;
    int c = tid & 127;
    float S = wsf[tensor*256 + c];
    float Q = wsf[tensor*256 + 128 + c];
    const float N = 262144.f;
    float mean = S / N;
    float var = fmaxf((Q - S*S/N) / (N - 1.f), 0.f);
    float inv = 1.f/(sqrtf(var)+EPSF);
    wsf[WS_CST + c*4 + tensor*2 + 0] = inv;
    wsf[WS_CST + c*4 + tensor*2 + 1] = mean*inv;
  }
  if (tid==0){
    float m = -1e30f;
    for (int i=0;i<9;i++) m = fmaxf(m, lw[i]);
    float e[9], sum=0.f;
    for (int i=0;i<9;i++){ e[i]=expf(lw[i]-m); sum+=e[i]; }
    for (int i=0;i<9;i++) wsf[WS_WGT+i] = e[i]/sum;
  }
}

// main kernel: thread = one pixel; channel loop is the outer sequential loop.
// Wave reads 64 consecutive pixels of one channel plane per load (256B,
// perfectly coalesced). All channel reductions are thread-local registers:
// no barriers, no cross-thread combine. SID = second loop over the same
// (now cache-warm) planes.
__global__ __launch_bounds__(256) void mainKernel(const float* __restrict__ rec,
                                                  const float* __restrict__ tgt,
                                                  const float* __restrict__ wsf,
                                                  unsigned* __restrict__ wsu,
                                                  float* __restrict__ errMap){
  __shared__ float4 cst[128];    // (i_p, m_p*i_p, i_t, m_t*i_t)
  __shared__ float wgt[12];
  __shared__ float rmn[4], rmx[4];
  int tid = threadIdx.x;
  if (tid < 128) cst[tid] = ((const float4*)(wsf + WS_CST))[tid];
  if (tid < 9)  wgt[tid] = wsf[WS_WGT + tid];
  __syncthreads();

  int pix = blockIdx.x*256 + tid;
  int b = pix >> 16;
  int hw = pix & (HWSZ-1);
  const float* pP = rec + ((size_t)b*CCH)*HWSZ + hw;
  const float* tP = tgt + ((size_t)b*CCH)*HWSZ + hw;

  float psum=0,psumsq=0,tsum=0,tsumsq=0,ptsum=0;
  float pmin=3.4e38f,pmax=-3.4e38f,tmin=3.4e38f,tmax=-3.4e38f;
  float bS1=0,bS11=0,bS2=0,bS22=0,bS12=0,bMp=3.4e38f,bMt=3.4e38f;

  #pragma unroll 8
  for (int c=0;c<CCH;c++){
    float pv = pP[(size_t)c*HWSZ];
    float tv = tP[(size_t)c*HWSZ];
    float4 k = cst[c];
    psum+=pv; psumsq=fmaf(pv,pv,psumsq);
    tsum+=tv; tsumsq=fmaf(tv,tv,tsumsq);
    ptsum=fmaf(pv,tv,ptsum);
    pmin=fminf(pmin,pv); pmax=fmaxf(pmax,pv);
    tmin=fminf(tmin,tv); tmax=fmaxf(tmax,tv);
    float bp = fmaf(pv, k.x, -k.y);
    float bt = fmaf(tv, k.z, -k.w);
    bS1+=bp; bS11=fmaf(bp,bp,bS11);
    bS2+=bt; bS22=fmaf(bt,bt,bS22);
    bS12=fmaf(bp,bt,bS12);
    bMp=fminf(bMp,bp); bMt=fminf(bMt,bt);
  }

  const float Ci = 1.0f/128.0f;
  float smm_p = 1.f/(pmax-pmin+EPSF);
  float smm_t = 1.f/(tmax-tmin+EPSF);
  float mean_p = psum*Ci, mean_t = tsum*Ci;
  float var_p = fmaxf((psumsq - psum*psum*Ci)*(1.f/127.f), 0.f);
  float var_t = fmaxf((tsumsq - tsum*tsum*Ci)*(1.f/127.f), 0.f);
  float zi_p = 1.f/(sqrtf(var_p)+EPSF);
  float zi_t = 1.f/(sqrtf(var_t)+EPSF);

  auto metrics = [](float S1,float S11,float S2,float S22,float S12,
                    float& sam,float& pear){
    float npn = fmaxf(sqrtf(fmaxf(S11,0.f)), EPSF);
    float ntn = fmaxf(sqrtf(fmaxf(S22,0.f)), EPSF);
    sam = 1.f - S12/(npn*ntn);
    const float ci = 1.0f/128.0f;
    float cov = S12 - S1*S2*ci;
    float vp = fmaxf(S11 - S1*S1*ci, 0.f);
    float vt = fmaxf(S22 - S2*S2*ci, 0.f);
    pear = 1.f - cov/(sqrtf(vp+EPSF)*sqrtf(vt+EPSF));
  };
  auto affine = [&](float ap,float sp,float at,float st,float& sam,float& pear){
    float S1 = (psum - 128.f*ap)*sp;
    float S11 = (psumsq - 2.f*ap*psum + 128.f*ap*ap)*sp*sp;
    float S2 = (tsum - 128.f*at)*st;
    float S22 = (tsumsq - 2.f*at*tsum + 128.f*at*at)*st*st;
    float S12 = (ptsum - at*psum - ap*tsum + 128.f*ap*at)*sp*st;
    metrics(S1,S11,S2,S22,S12,sam,pear);
  };

  float sam_mm,pear_mm,sam_z,pear_z,sam_bn,pear_bn;
  affine(pmin,smm_p,tmin,smm_t,sam_mm,pear_mm);
  affine(mean_p,zi_p,mean_t,zi_t,sam_z,pear_z);
  metrics(bS1,bS11,bS2,bS22,bS12,sam_bn,pear_bn);

  // SID constants (minmax/z shared; bn separate)
  float dp = fmaf(psum - 128.f*pmin, smm_p, EPSF);
  float fp = smm_p/dp;  float Bp = pmin*fp;
  float dt = fmaf(tsum - 128.f*tmin, smm_t, EPSF);
  float ft = smm_t/dt;  float Bt = tmin*ft;
  float fbp = 1.f/((bS1 - 128.f*bMp) + EPSF); float Bbp = bMp*fbp;
  float fbt = 1.f/((bS2 - 128.f*bMt) + EPSF); float Bbt = bMt*fbt;

  float sid_mm=0.f, sid_bn=0.f;
  #pragma unroll 8
  for (int c=0;c<CCH;c++){
    float pv = pP[(size_t)c*HWSZ];
    float tv = tP[(size_t)c*HWSZ];
    float4 k = cst[c];
    float pp = fmaxf(fmaf(pv,fp,-Bp), EPSF);
    float tp = fmaxf(fmaf(tv,ft,-Bt), EPSF);
    sid_mm = fmaf(pp-tp, __log2f(pp)-__log2f(tp), sid_mm);
    float bp = fmaf(pv, k.x, -k.y);
    float bt = fmaf(tv, k.z, -k.w);
    float qp = fmaxf(fmaf(bp,fbp,-Bbp), EPSF);
    float qt = fmaxf(fmaf(bt,fbt,-Bbt), EPSF);
    sid_bn = fmaf(qp-qt, __log2f(qp)-__log2f(qt), sid_bn);
  }
  sid_mm *= LN2F; sid_bn *= LN2F;

  float err = wgt[0]*sam_mm + wgt[1]*pear_mm + (wgt[2]+wgt[5])*sid_mm
            + wgt[3]*sam_z  + wgt[4]*pear_z
            + wgt[6]*sam_bn + wgt[7]*pear_bn + wgt[8]*sid_bn;
  errMap[pix] = err;

  // block min/max -> 2 atomics per block
  float emin = err, emax = err;
  #pragma unroll
  for (int off=1; off<64; off<<=1){
    emin = fminf(emin, __shfl_xor(emin,off));
    emax = fmaxf(emax, __shfl_xor(emax,off));
  }
  int w = tid>>6;
  if ((tid&63)==0){ rmn[w]=emin; rmx[w]=emax; }
  __syncthreads();
  if (tid==0){
    emin = fminf(fminf(rmn[0],rmn[1]),fminf(rmn[2],rmn[3]));
    emax = fmaxf(fmaxf(rmx[0],rmx[1]),fmaxf(rmx[2],rmx[3]));
    atomicMin(&wsu[WS_MINKEY], fkey(emin));
    atomicMax(&wsu[WS_MAXKEY], fkey(emax));
  }
}

__global__ __launch_bounds__(256) void hist1Kernel(const float* __restrict__ err,
                                                   unsigned* __restrict__ wsu){
  __shared__ unsigned h[4096];
  int tid = threadIdx.x;
  for (int i=tid;i<4096;i+=256) h[i]=0u;
  __syncthreads();
  float lo = funkey(wsu[WS_MINKEY]);
  float hi = funkey(wsu[WS_MAXKEY]);
  float invw = 4096.f / fmaxf(hi-lo, 1e-30f);
  int base = blockIdx.x*2048 + tid;
  for (int j=0;j<8;j++){
    float v = err[base + j*256];
    int idx = (int)fminf(fmaxf((v-lo)*invw, 0.f), 4095.f);
    atomicAdd(&h[idx], 1u);
  }
  __syncthreads();
  for (int i=tid;i<4096;i+=256){ unsigned c=h[i]; if (c) atomicAdd(&wsu[WS_H1+i], c); }
}

__global__ __launch_bounds__(256) void scan1Kernel(float* __restrict__ wsf,
                                                   unsigned* __restrict__ wsu){
  __shared__ unsigned counts[4096];
  __shared__ unsigned s[256];
  int tid = threadIdx.x;
  for (int i=tid;i<4096;i+=256) counts[i]=wsu[WS_H1+i];
  __syncthreads();
  unsigned part=0;
  for (int j=0;j<16;j++) part += counts[tid*16+j];
  s[tid]=part; __syncthreads();
  for (int off=1; off<256; off<<=1){
    unsigned v = (tid+off<256)? s[tid+off] : 0u;
    __syncthreads();
    s[tid] += v;
    __syncthreads();
  }
  float lo = funkey(wsu[WS_MINKEY]);
  float hi = funkey(wsu[WS_MAXKEY]);
  float w1 = fmaxf(hi-lo, 1e-30f) * (1.f/4096.f);
  unsigned cum = (tid<255)? s[tid+1] : 0u;
  for (int j=15;j>=0;j--){
    int bin = tid*16+j;
    unsigned cn = cum + counts[bin];
    if (cum < (unsigned)KTOP && cn >= (unsigned)KTOP){
      wsu[WS_BSTAR] = (unsigned)bin;
      wsu[WS_CNTAB] = cum;
      wsu[WS_K2]    = (unsigned)KTOP - cum;
      wsf[WS_LO2]   = lo + (float)bin*w1;
      wsf[WS_W2]    = w1*(1.f/4096.f);
    }
    cum = cn;
  }
}

__global__ __launch_bounds__(256) void hist2Kernel(const float* __restrict__ err,
                                                   float* __restrict__ wsf,
                                                   unsigned* __restrict__ wsu){
  __shared__ unsigned h2[4096];
  __shared__ float s2[4096];
  __shared__ float ls[4];
  int tid = threadIdx.x;
  for (int i=tid;i<4096;i+=256){ h2[i]=0u; s2[i]=0.f; }
  __syncthreads();
  float lo = funkey(wsu[WS_MINKEY]);
  float hi = funkey(wsu[WS_MAXKEY]);
  float invw = 4096.f / fmaxf(hi-lo, 1e-30f);
  int bstar = (int)wsu[WS_BSTAR];
  float lo2 = wsf[WS_LO2];
  float w2  = wsf[WS_W2];
  float invw2 = 1.f / w2;
  float mySum = 0.f;
  int base = blockIdx.x*2048 + tid;
  for (int j=0;j<8;j++){
    float v = err[base + j*256];
    int idx = (int)fminf(fmaxf((v-lo)*invw, 0.f), 4095.f);
    if (idx > bstar){
      mySum += v;
    } else if (idx == bstar){
      int i2 = (int)fminf(fmaxf((v-lo2)*invw2, 0.f), 4095.f);
      atomicAdd(&h2[i2], 1u);
      atomicAdd(&s2[i2], v);
    }
  }
  for (int off=1; off<64; off<<=1) mySum += __shfl_xor(mySum, off);
  if ((tid&63)==0) ls[tid>>6] = mySum;
  __syncthreads();
  if (tid==0) atomicAdd(&wsf[WS_SUMAB], ls[0]+ls[1]+ls[2]+ls[3]);
  for (int i=tid;i<4096;i+=256){
    unsigned c = h2[i]; if (c) atomicAdd(&wsu[WS_H2C+i], c);
    float sv = s2[i];   if (sv != 0.f) atomicAdd(&wsf[WS_H2S+i], sv);
  }
}

__global__ __launch_bounds__(256) void scan2Kernel(float* __restrict__ wsf,
                                                   unsigned* __restrict__ wsu,
                                                   float* __restrict__ out){
  __shared__ unsigned cnt[4096];
  __shared__ float sm[4096];
  __shared__ unsigned sC[256];
  __shared__ float sS[256];
  int tid = threadIdx.x;
  for (int i=tid;i<4096;i+=256){ cnt[i]=wsu[WS_H2C+i]; sm[i]=wsf[WS_H2S+i]; }
  __syncthreads();
  unsigned pc=0; float ps=0.f;
  for (int j=0;j<16;j++){ pc+=cnt[tid*16+j]; ps+=sm[tid*16+j]; }
  sC[tid]=pc; sS[tid]=ps; __syncthreads();
  for (int off=1; off<256; off<<=1){
    unsigned vc = (tid+off<256)? sC[tid+off] : 0u;
    float vs    = (tid+off<256)? sS[tid+off] : 0.f;
    __syncthreads();
    sC[tid] += vc; sS[tid] += vs;
    __syncthreads();
  }
  unsigned k2 = wsu[WS_K2];
  float lo2 = wsf[WS_LO2], w2 = wsf[WS_W2];
  unsigned cum = (tid<255)? sC[tid+1] : 0u;
  float cums   = (tid<255)? sS[tid+1] : 0.f;
  for (int j=15;j>=0;j--){
    int bin = tid*16+j;
    unsigned cn = cum + cnt[bin];
    float sn = cums + sm[bin];
    if (cum < k2 && cn >= k2){
      float val = lo2 + ((float)bin + 0.5f)*w2;
      float total = wsf[WS_SUMAB] + cums + (float)(k2 - cum)*val;
      out[0] = total / (float)KTOP;
    }
    cum = cn; cums = sn;
  }
}

extern "C" void kernel_launch(void* const* d_in, const int* in_sizes, int n_in,
                              void* d_out, int out_size, void* d_ws, size_t ws_size,
                              hipStream_t stream){
  const float* rec = (const float*)d_in[0];
  const float* tgt = (const float*)d_in[1];
  const float* lw  = (const float*)d_in[2];
  float* out = (float*)d_out;
  float* wsf = (float*)d_ws;
  unsigned* wsu = (unsigned*)d_ws;

  hipLaunchKernelGGL(initWs, dim3((WS_TOTAL+255)/256), dim3(256), 0, stream, wsu);
  hipLaunchKernelGGL(bnSumKernel, dim3(1024), dim3(512), 0, stream, rec, tgt, wsf);
  hipLaunchKernelGGL(finalizeKernel, dim3(1), dim3(256), 0, stream, lw, wsf);
  hipLaunchKernelGGL(mainKernel, dim3(NPIX/256), dim3(256), 0, stream, rec, tgt, wsf, wsu, out+1);
  hipLaunchKernelGGL(hist1Kernel, dim3(128), dim3(256), 0, stream, out+1, wsu);
  hipLaunchKernelGGL(scan1Kernel, dim3(1), dim3(256), 0, stream, wsf, wsu);
  hipLaunchKernelGGL(hist2Kernel, dim3(128), dim3(256), 0, stream, out+1, wsf, wsu);
  hipLaunchKernelGGL(scan2Kernel, dim3(1), dim3(256), 0, stream, wsf, wsu, out);
}

// Round 7
// 162.199 us; speedup vs baseline: 1.8726x; 1.2251x over previous
//
#include <hip/hip_runtime.h>

#define EPSF 1e-8f
#define CCH 128
#define HWSZ 65536
#define NPIX 262144
#define KTOP 13107
#define LN2F 0.6931471805599453f

// ws layout (32-bit words)
#define WS_SUM    0      // [512] f32: sumP[128], sumsqP[128], sumT[128], sumsqT[128]
#define WS_CST    512    // [512] f32: float4 per channel c: (i_p, m_p*i_p, i_t, m_t*i_t)
#define WS_WGT    1024   // [9] f32 softmax weights
#define WS_MINKEY 1040
#define WS_MAXKEY 1041
#define WS_BSTAR  1042
#define WS_CNTAB  1043
#define WS_LO2    1044
#define WS_W2     1045
#define WS_K2     1046
#define WS_SUMAB  1048
#define WS_H1     1056   // [4096] u32
#define WS_H2C    5152   // [4096] u32
#define WS_H2S    9248   // [4096] f32
#define WS_TOTAL  13344

__device__ __forceinline__ unsigned fkey(float f){
  unsigned u = __float_as_uint(f);
  return (u & 0x80000000u) ? ~u : (u | 0x80000000u);
}
__device__ __forceinline__ float funkey(unsigned k){
  unsigned u = (k & 0x80000000u) ? (k & 0x7fffffffu) : ~k;
  return __uint_as_float(u);
}

struct Stats {
  float psum,psumsq,tsum,tsumsq,ptsum,pmin,pmax,tmin,tmax;
  float bS1,bS11,bS2,bS22,bS12,bMp,bMt;
};
struct Consts { float errBase,fp,Bp,ft,Bt,fbp,Bbp,fbt,Bbt,sidW,bnW; };

__device__ Consts pixEpilogue(const Stats& s, const float* wgt){
  const float Ci = 1.0f/128.0f;
  float smm_p = 1.f/(s.pmax-s.pmin+EPSF);
  float smm_t = 1.f/(s.tmax-s.tmin+EPSF);
  float mean_p = s.psum*Ci, mean_t = s.tsum*Ci;
  float var_p = fmaxf((s.psumsq - s.psum*s.psum*Ci)*(1.f/127.f), 0.f);
  float var_t = fmaxf((s.tsumsq - s.tsum*s.tsum*Ci)*(1.f/127.f), 0.f);
  float zi_p = 1.f/(sqrtf(var_p)+EPSF);
  float zi_t = 1.f/(sqrtf(var_t)+EPSF);

  auto metrics = [&](float S1,float S11,float S2,float S22,float S12,
                     float& sam,float& pear){
    float npn = fmaxf(sqrtf(fmaxf(S11,0.f)), EPSF);
    float ntn = fmaxf(sqrtf(fmaxf(S22,0.f)), EPSF);
    sam = 1.f - S12/(npn*ntn);
    float cov = S12 - S1*S2*Ci;
    float vp = fmaxf(S11 - S1*S1*Ci, 0.f);
    float vt = fmaxf(S22 - S2*S2*Ci, 0.f);
    pear = 1.f - cov/(sqrtf(vp+EPSF)*sqrtf(vt+EPSF));
  };
  auto affine = [&](float ap,float sp,float at,float st,float& sam,float& pear){
    float S1 = (s.psum - 128.f*ap)*sp;
    float S11 = (s.psumsq - 2.f*ap*s.psum + 128.f*ap*ap)*sp*sp;
    float S2 = (s.tsum - 128.f*at)*st;
    float S22 = (s.tsumsq - 2.f*at*s.tsum + 128.f*at*at)*st*st;
    float S12 = (s.ptsum - at*s.psum - ap*s.tsum + 128.f*ap*at)*sp*st;
    metrics(S1,S11,S2,S22,S12,sam,pear);
  };

  float sam_mm,pear_mm,sam_z,pear_z,sam_bn,pear_bn;
  affine(s.pmin,smm_p,s.tmin,smm_t,sam_mm,pear_mm);
  affine(mean_p,zi_p,mean_t,zi_t,sam_z,pear_z);
  metrics(s.bS1,s.bS11,s.bS2,s.bS22,s.bS12,sam_bn,pear_bn);

  Consts c;
  c.errBase = wgt[0]*sam_mm + wgt[1]*pear_mm + wgt[3]*sam_z + wgt[4]*pear_z
            + wgt[6]*sam_bn + wgt[7]*pear_bn;
  float dp = fmaf(s.psum - 128.f*s.pmin, smm_p, EPSF);
  c.fp = smm_p/dp;  c.Bp = s.pmin*c.fp;
  float dt = fmaf(s.tsum - 128.f*s.tmin, smm_t, EPSF);
  c.ft = smm_t/dt;  c.Bt = s.tmin*c.ft;
  c.fbp = 1.f/((s.bS1 - 128.f*s.bMp) + EPSF); c.Bbp = s.bMp*c.fbp;
  c.fbt = 1.f/((s.bS2 - 128.f*s.bMt) + EPSF); c.Bbt = s.bMt*c.fbt;
  c.sidW = (wgt[2]+wgt[5])*LN2F;
  c.bnW  = wgt[8]*LN2F;
  return c;
}

__global__ __launch_bounds__(256) void initWs(unsigned* __restrict__ wsu){
  int idx = blockIdx.x*256 + threadIdx.x;
  if (idx < WS_TOTAL) wsu[idx] = (idx == WS_MINKEY) ? 0xFFFFFFFFu : 0u;
}

// per-channel sums over (B,H,W) for both tensors
__global__ __launch_bounds__(512) void bnSumKernel(const float* __restrict__ rec,
                                                   const float* __restrict__ tgt,
                                                   float* __restrict__ wsf){
  int blk = blockIdx.x;            // 0..1023: tensor(2) x b(4) x c(128)
  int tensor = blk >> 9;
  int rem = blk & 511;
  int c = rem & 127;
  int b = rem >> 7;
  const float* src = (tensor==0 ? rec : tgt) + ((size_t)(b*CCH + c))*HWSZ;
  const float4* src4 = (const float4*)src;
  float s=0.f, q=0.f;
  #pragma unroll 4
  for (int j=threadIdx.x; j<HWSZ/4; j+=512){
    float4 v = src4[j];
    s += v.x+v.y+v.z+v.w;
    q += v.x*v.x + v.y*v.y + v.z*v.z + v.w*v.w;
  }
  for (int off=1; off<64; off<<=1){ s += __shfl_xor(s,off); q += __shfl_xor(q,off); }
  __shared__ float ls[8], lq[8];
  int wid = threadIdx.x >> 6;
  if ((threadIdx.x & 63)==0){ ls[wid]=s; lq[wid]=q; }
  __syncthreads();
  if (threadIdx.x==0){
    float S=0,Q=0;
    for (int i=0;i<8;i++){ S+=ls[i]; Q+=lq[i]; }
    atomicAdd(&wsf[tensor*256 + c], S);
    atomicAdd(&wsf[tensor*256 + 128 + c], Q);
  }
}

// bn inv-std and mean*inv-std per channel (both tensors) + softmax weights
__global__ __launch_bounds__(256) void finalizeKernel(const float* __restrict__ lw,
                                                      float* __restrict__ wsf){
  int tid = threadIdx.x;
  {
    int tensor = tid >> 7;
    int c = tid & 127;
    float S = wsf[tensor*256 + c];
    float Q = wsf[tensor*256 + 128 + c];
    const float N = 262144.f;
    float mean = S / N;
    float var = fmaxf((Q - S*S/N) / (N - 1.f), 0.f);
    float inv = 1.f/(sqrtf(var)+EPSF);
    wsf[WS_CST + c*4 + tensor*2 + 0] = inv;
    wsf[WS_CST + c*4 + tensor*2 + 1] = mean*inv;
  }
  if (tid==0){
    float m = -1e30f;
    for (int i=0;i<9;i++) m = fmaxf(m, lw[i]);
    float e[9], sum=0.f;
    for (int i=0;i<9;i++){ e[i]=expf(lw[i]-m); sum+=e[i]; }
    for (int i=0;i<9;i++) wsf[WS_WGT+i] = e[i]/sum;
  }
}

// main kernel: thread = 2 consecutive pixels (float2 loads -> 512B/wave-instr).
// Channel loop in batches of 8 with all 16 loads issued before consumption.
__global__ __launch_bounds__(256, 4) void mainKernel(const float* __restrict__ rec,
                                                     const float* __restrict__ tgt,
                                                     const float* __restrict__ wsf,
                                                     unsigned* __restrict__ wsu,
                                                     float* __restrict__ errMap){
  __shared__ float4 cst[128];    // (i_p, m_p*i_p, i_t, m_t*i_t)
  __shared__ float wgtS[12];
  __shared__ float rmn[4], rmx[4];
  int tid = threadIdx.x;
  if (tid < 128) cst[tid] = ((const float4*)(wsf + WS_CST))[tid];
  if (tid < 9)  wgtS[tid] = wsf[WS_WGT + tid];
  __syncthreads();

  int pix0 = blockIdx.x*512 + tid*2;
  int b = pix0 >> 16;
  unsigned hwb = (unsigned)(pix0 & (HWSZ-1)) * 4u;
  const char* pB = (const char*)(rec + ((size_t)b*CCH)*HWSZ) + hwb;
  const char* tB = (const char*)(tgt + ((size_t)b*CCH)*HWSZ) + hwb;

  float2 psum={0,0},psumsq={0,0},tsum={0,0},tsumsq={0,0},ptsum={0,0};
  float2 pmin={3.4e38f,3.4e38f},pmax={-3.4e38f,-3.4e38f};
  float2 tmin={3.4e38f,3.4e38f},tmax={-3.4e38f,-3.4e38f};
  float2 bS1={0,0},bS11={0,0},bS2={0,0},bS22={0,0},bS12={0,0};
  float2 bMp={3.4e38f,3.4e38f},bMt={3.4e38f,3.4e38f};

  for (int cb=0; cb<CCH; cb+=8){
    float2 P[8], T[8];
    #pragma unroll
    for (int j=0;j<8;j++){
      P[j] = *(const float2*)(pB + ((unsigned)(cb+j)<<18));
      T[j] = *(const float2*)(tB + ((unsigned)(cb+j)<<18));
    }
    #pragma unroll
    for (int j=0;j<8;j++){
      float4 k = cst[cb+j];
      float2 pv=P[j], tv=T[j];
      psum.x+=pv.x; psum.y+=pv.y;
      psumsq.x=fmaf(pv.x,pv.x,psumsq.x); psumsq.y=fmaf(pv.y,pv.y,psumsq.y);
      tsum.x+=tv.x; tsum.y+=tv.y;
      tsumsq.x=fmaf(tv.x,tv.x,tsumsq.x); tsumsq.y=fmaf(tv.y,tv.y,tsumsq.y);
      ptsum.x=fmaf(pv.x,tv.x,ptsum.x); ptsum.y=fmaf(pv.y,tv.y,ptsum.y);
      pmin.x=fminf(pmin.x,pv.x); pmin.y=fminf(pmin.y,pv.y);
      pmax.x=fmaxf(pmax.x,pv.x); pmax.y=fmaxf(pmax.y,pv.y);
      tmin.x=fminf(tmin.x,tv.x); tmin.y=fminf(tmin.y,tv.y);
      tmax.x=fmaxf(tmax.x,tv.x); tmax.y=fmaxf(tmax.y,tv.y);
      float bpx = fmaf(pv.x,k.x,-k.y), bpy = fmaf(pv.y,k.x,-k.y);
      float btx = fmaf(tv.x,k.z,-k.w), bty = fmaf(tv.y,k.z,-k.w);
      bS1.x+=bpx; bS1.y+=bpy;
      bS11.x=fmaf(bpx,bpx,bS11.x); bS11.y=fmaf(bpy,bpy,bS11.y);
      bS2.x+=btx; bS2.y+=bty;
      bS22.x=fmaf(btx,btx,bS22.x); bS22.y=fmaf(bty,bty,bS22.y);
      bS12.x=fmaf(bpx,btx,bS12.x); bS12.y=fmaf(bpy,bty,bS12.y);
      bMp.x=fminf(bMp.x,bpx); bMp.y=fminf(bMp.y,bpy);
      bMt.x=fminf(bMt.x,btx); bMt.y=fminf(bMt.y,bty);
    }
  }

  Stats sx = {psum.x,psumsq.x,tsum.x,tsumsq.x,ptsum.x,pmin.x,pmax.x,tmin.x,tmax.x,
              bS1.x,bS11.x,bS2.x,bS22.x,bS12.x,bMp.x,bMt.x};
  Stats sy = {psum.y,psumsq.y,tsum.y,tsumsq.y,ptsum.y,pmin.y,pmax.y,tmin.y,tmax.y,
              bS1.y,bS11.y,bS2.y,bS22.y,bS12.y,bMp.y,bMt.y};
  Consts cx = pixEpilogue(sx, wgtS);
  Consts cy = pixEpilogue(sy, wgtS);

  float2 sid_mm={0,0}, sid_bn={0,0};
  for (int cb=0; cb<CCH; cb+=8){
    float2 P[8], T[8];
    #pragma unroll
    for (int j=0;j<8;j++){
      P[j] = *(const float2*)(pB + ((unsigned)(cb+j)<<18));
      T[j] = *(const float2*)(tB + ((unsigned)(cb+j)<<18));
    }
    #pragma unroll
    for (int j=0;j<8;j++){
      float4 k = cst[cb+j];
      float2 pv=P[j], tv=T[j];
      float ppx = fmaxf(fmaf(pv.x,cx.fp,-cx.Bp), EPSF);
      float tpx = fmaxf(fmaf(tv.x,cx.ft,-cx.Bt), EPSF);
      sid_mm.x = fmaf(ppx-tpx, __log2f(ppx)-__log2f(tpx), sid_mm.x);
      float ppy = fmaxf(fmaf(pv.y,cy.fp,-cy.Bp), EPSF);
      float tpy = fmaxf(fmaf(tv.y,cy.ft,-cy.Bt), EPSF);
      sid_mm.y = fmaf(ppy-tpy, __log2f(ppy)-__log2f(tpy), sid_mm.y);
      float bpx = fmaf(pv.x,k.x,-k.y), bpy = fmaf(pv.y,k.x,-k.y);
      float btx = fmaf(tv.x,k.z,-k.w), bty = fmaf(tv.y,k.z,-k.w);
      float qpx = fmaxf(fmaf(bpx,cx.fbp,-cx.Bbp), EPSF);
      float qtx = fmaxf(fmaf(btx,cx.fbt,-cx.Bbt), EPSF);
      sid_bn.x = fmaf(qpx-qtx, __log2f(qpx)-__log2f(qtx), sid_bn.x);
      float qpy = fmaf(bpy,cy.fbp,-cy.Bbp);  qpy = fmaxf(qpy, EPSF);
      float qty = fmaf(bty,cy.fbt,-cy.Bbt);  qty = fmaxf(qty, EPSF);
      sid_bn.y = fmaf(qpy-qty, __log2f(qpy)-__log2f(qty), sid_bn.y);
    }
  }

  float errx = cx.errBase + cx.sidW*sid_mm.x + cx.bnW*sid_bn.x;
  float erry = cy.errBase + cy.sidW*sid_mm.y + cy.bnW*sid_bn.y;
  errMap[pix0]   = errx;
  errMap[pix0+1] = erry;

  float emin = fminf(errx,erry), emax = fmaxf(errx,erry);
  #pragma unroll
  for (int off=1; off<64; off<<=1){
    emin = fminf(emin, __shfl_xor(emin,off));
    emax = fmaxf(emax, __shfl_xor(emax,off));
  }
  int w = tid>>6;
  if ((tid&63)==0){ rmn[w]=emin; rmx[w]=emax; }
  __syncthreads();
  if (tid==0){
    emin = fminf(fminf(rmn[0],rmn[1]),fminf(rmn[2],rmn[3]));
    emax = fmaxf(fmaxf(rmx[0],rmx[1]),fmaxf(rmx[2],rmx[3]));
    atomicMin(&wsu[WS_MINKEY], fkey(emin));
    atomicMax(&wsu[WS_MAXKEY], fkey(emax));
  }
}

__global__ __launch_bounds__(256) void hist1Kernel(const float* __restrict__ err,
                                                   unsigned* __restrict__ wsu){
  __shared__ unsigned h[4096];
  int tid = threadIdx.x;
  for (int i=tid;i<4096;i+=256) h[i]=0u;
  __syncthreads();
  float lo = funkey(wsu[WS_MINKEY]);
  float hi = funkey(wsu[WS_MAXKEY]);
  float invw = 4096.f / fmaxf(hi-lo, 1e-30f);
  int base = blockIdx.x*2048 + tid;
  for (int j=0;j<8;j++){
    float v = err[base + j*256];
    int idx = (int)fminf(fmaxf((v-lo)*invw, 0.f), 4095.f);
    atomicAdd(&h[idx], 1u);
  }
  __syncthreads();
  for (int i=tid;i<4096;i+=256){ unsigned c=h[i]; if (c) atomicAdd(&wsu[WS_H1+i], c); }
}

__global__ __launch_bounds__(256) void scan1Kernel(float* __restrict__ wsf,
                                                   unsigned* __restrict__ wsu){
  __shared__ unsigned counts[4096];
  __shared__ unsigned s[256];
  int tid = threadIdx.x;
  for (int i=tid;i<4096;i+=256) counts[i]=wsu[WS_H1+i];
  __syncthreads();
  unsigned part=0;
  for (int j=0;j<16;j++) part += counts[tid*16+j];
  s[tid]=part; __syncthreads();
  for (int off=1; off<256; off<<=1){
    unsigned v = (tid+off<256)? s[tid+off] : 0u;
    __syncthreads();
    s[tid] += v;
    __syncthreads();
  }
  float lo = funkey(wsu[WS_MINKEY]);
  float hi = funkey(wsu[WS_MAXKEY]);
  float w1 = fmaxf(hi-lo, 1e-30f) * (1.f/4096.f);
  unsigned cum = (tid<255)? s[tid+1] : 0u;
  for (int j=15;j>=0;j--){
    int bin = tid*16+j;
    unsigned cn = cum + counts[bin];
    if (cum < (unsigned)KTOP && cn >= (unsigned)KTOP){
      wsu[WS_BSTAR] = (unsigned)bin;
      wsu[WS_CNTAB] = cum;
      wsu[WS_K2]    = (unsigned)KTOP - cum;
      wsf[WS_LO2]   = lo + (float)bin*w1;
      wsf[WS_W2]    = w1*(1.f/4096.f);
    }
    cum = cn;
  }
}

__global__ __launch_bounds__(256) void hist2Kernel(const float* __restrict__ err,
                                                   float* __restrict__ wsf,
                                                   unsigned* __restrict__ wsu){
  __shared__ unsigned h2[4096];
  __shared__ float s2[4096];
  __shared__ float ls[4];
  int tid = threadIdx.x;
  for (int i=tid;i<4096;i+=256){ h2[i]=0u; s2[i]=0.f; }
  __syncthreads();
  float lo = funkey(wsu[WS_MINKEY]);
  float hi = funkey(wsu[WS_MAXKEY]);
  float invw = 4096.f / fmaxf(hi-lo, 1e-30f);
  int bstar = (int)wsu[WS_BSTAR];
  float lo2 = wsf[WS_LO2];
  float w2  = wsf[WS_W2];
  float invw2 = 1.f / w2;
  float mySum = 0.f;
  int base = blockIdx.x*2048 + tid;
  for (int j=0;j<8;j++){
    float v = err[base + j*256];
    int idx = (int)fminf(fmaxf((v-lo)*invw, 0.f), 4095.f);
    if (idx > bstar){
      mySum += v;
    } else if (idx == bstar){
      int i2 = (int)fminf(fmaxf((v-lo2)*invw2, 0.f), 4095.f);
      atomicAdd(&h2[i2], 1u);
      atomicAdd(&s2[i2], v);
    }
  }
  for (int off=1; off<64; off<<=1) mySum += __shfl_xor(mySum, off);
  if ((tid&63)==0) ls[tid>>6] = mySum;
  __syncthreads();
  if (tid==0) atomicAdd(&wsf[WS_SUMAB], ls[0]+ls[1]+ls[2]+ls[3]);
  for (int i=tid;i<4096;i+=256){
    unsigned c = h2[i]; if (c) atomicAdd(&wsu[WS_H2C+i], c);
    float sv = s2[i];   if (sv != 0.f) atomicAdd(&wsf[WS_H2S+i], sv);
  }
}

__global__ __launch_bounds__(256) void scan2Kernel(float* __restrict__ wsf,
                                                   unsigned* __restrict__ wsu,
                                                   float* __restrict__ out){
  __shared__ unsigned cnt[4096];
  __shared__ float sm[4096];
  __shared__ unsigned sC[256];
  __shared__ float sS[256];
  int tid = threadIdx.x;
  for (int i=tid;i<4096;i+=256){ cnt[i]=wsu[WS_H2C+i]; sm[i]=wsf[WS_H2S+i]; }
  __syncthreads();
  unsigned pc=0; float ps=0.f;
  for (int j=0;j<16;j++){ pc+=cnt[tid*16+j]; ps+=sm[tid*16+j]; }
  sC[tid]=pc; sS[tid]=ps; __syncthreads();
  for (int off=1; off<256; off<<=1){
    unsigned vc = (tid+off<256)? sC[tid+off] : 0u;
    float vs    = (tid+off<256)? sS[tid+off] : 0.f;
    __syncthreads();
    sC[tid] += vc; sS[tid] += vs;
    __syncthreads();
  }
  unsigned k2 = wsu[WS_K2];
  float lo2 = wsf[WS_LO2], w2 = wsf[WS_W2];
  unsigned cum = (tid<255)? sC[tid+1] : 0u;
  float cums   = (tid<255)? sS[tid+1] : 0.f;
  for (int j=15;j>=0;j--){
    int bin = tid*16+j;
    unsigned cn = cum + cnt[bin];
    float sn = cums + sm[bin];
    if (cum < k2 && cn >= k2){
      float val = lo2 + ((float)bin + 0.5f)*w2;
      float total = wsf[WS_SUMAB] + cums + (float)(k2 - cum)*val;
      out[0] = total / (float)KTOP;
    }
    cum = cn; cums = sn;
  }
}

extern "C" void kernel_launch(void* const* d_in, const int* in_sizes, int n_in,
                              void* d_out, int out_size, void* d_ws, size_t ws_size,
                              hipStream_t stream){
  const float* rec = (const float*)d_in[0];
  const float* tgt = (const float*)d_in[1];
  const float* lw  = (const float*)d_in[2];
  float* out = (float*)d_out;
  float* wsf = (float*)d_ws;
  unsigned* wsu = (unsigned*)d_ws;

  hipLaunchKernelGGL(initWs, dim3((WS_TOTAL+255)/256), dim3(256), 0, stream, wsu);
  hipLaunchKernelGGL(bnSumKernel, dim3(1024), dim3(512), 0, stream, rec, tgt, wsf);
  hipLaunchKernelGGL(finalizeKernel, dim3(1), dim3(256), 0, stream, lw, wsf);
  hipLaunchKernelGGL(mainKernel, dim3(NPIX/512), dim3(256), 0, stream, rec, tgt, wsf, wsu, out+1);
  hipLaunchKernelGGL(hist1Kernel, dim3(128), dim3(256), 0, stream, out+1, wsu);
  hipLaunchKernelGGL(scan1Kernel, dim3(1), dim3(256), 0, stream, wsf, wsu);
  hipLaunchKernelGGL(hist2Kernel, dim3(128), dim3(256), 0, stream, out+1, wsf, wsu);
  hipLaunchKernelGGL(scan2Kernel, dim3(1), dim3(256), 0, stream, wsf, wsu, out);
}

// Round 8
// 159.848 us; speedup vs baseline: 1.9001x; 1.0147x over previous
//
#include <hip/hip_runtime.h>

#define EPSF 1e-8f
#define CCH 128
#define HWSZ 65536
#define NPIX 262144
#define KTOP 13107
#define LN2F 0.6931471805599453f

// ws layout (32-bit words)
#define WS_SUM    0      // [512] f32: sumP[128], sumsqP[128], sumT[128], sumsqT[128]
#define WS_CST    512    // [512] f32: float4 per channel c: (i_p, m_p*i_p, i_t, m_t*i_t)
#define WS_WGT    1024   // [9] f32 softmax weights
#define WS_MINKEY 1040
#define WS_MAXKEY 1041
#define WS_BSTAR  1042
#define WS_CNTAB  1043
#define WS_LO2    1044
#define WS_W2     1045
#define WS_K2     1046
#define WS_SUMAB  1048
#define WS_H1     1056   // [4096] u32
#define WS_H2C    5152   // [4096] u32
#define WS_H2S    9248   // [4096] f32
#define WS_TOTAL  13344

__device__ __forceinline__ unsigned fkey(float f){
  unsigned u = __float_as_uint(f);
  return (u & 0x80000000u) ? ~u : (u | 0x80000000u);
}
__device__ __forceinline__ float funkey(unsigned k){
  unsigned u = (k & 0x80000000u) ? (k & 0x7fffffffu) : ~k;
  return __uint_as_float(u);
}

struct Stats {
  float psum,psumsq,tsum,tsumsq,ptsum,pmin,pmax,tmin,tmax;
  float bS1,bS11,bS2,bS22,bS12,bMp,bMt;
};
struct Consts { float errBase,fp,Bp,ft,Bt,fbp,Bbp,fbt,Bbt,sidW,bnW; };

__device__ Consts pixEpilogue(const Stats& s, const float* wgt){
  const float Ci = 1.0f/128.0f;
  float smm_p = 1.f/(s.pmax-s.pmin+EPSF);
  float smm_t = 1.f/(s.tmax-s.tmin+EPSF);
  float mean_p = s.psum*Ci, mean_t = s.tsum*Ci;
  float var_p = fmaxf((s.psumsq - s.psum*s.psum*Ci)*(1.f/127.f), 0.f);
  float var_t = fmaxf((s.tsumsq - s.tsum*s.tsum*Ci)*(1.f/127.f), 0.f);
  float zi_p = 1.f/(sqrtf(var_p)+EPSF);
  float zi_t = 1.f/(sqrtf(var_t)+EPSF);

  auto metrics = [&](float S1,float S11,float S2,float S22,float S12,
                     float& sam,float& pear){
    float npn = fmaxf(sqrtf(fmaxf(S11,0.f)), EPSF);
    float ntn = fmaxf(sqrtf(fmaxf(S22,0.f)), EPSF);
    sam = 1.f - S12/(npn*ntn);
    float cov = S12 - S1*S2*Ci;
    float vp = fmaxf(S11 - S1*S1*Ci, 0.f);
    float vt = fmaxf(S22 - S2*S2*Ci, 0.f);
    pear = 1.f - cov/(sqrtf(vp+EPSF)*sqrtf(vt+EPSF));
  };
  auto affine = [&](float ap,float sp,float at,float st,float& sam,float& pear){
    float S1 = (s.psum - 128.f*ap)*sp;
    float S11 = (s.psumsq - 2.f*ap*s.psum + 128.f*ap*ap)*sp*sp;
    float S2 = (s.tsum - 128.f*at)*st;
    float S22 = (s.tsumsq - 2.f*at*s.tsum + 128.f*at*at)*st*st;
    float S12 = (s.ptsum - at*s.psum - ap*s.tsum + 128.f*ap*at)*sp*st;
    metrics(S1,S11,S2,S22,S12,sam,pear);
  };

  float sam_mm,pear_mm,sam_z,pear_z,sam_bn,pear_bn;
  affine(s.pmin,smm_p,s.tmin,smm_t,sam_mm,pear_mm);
  affine(mean_p,zi_p,mean_t,zi_t,sam_z,pear_z);
  metrics(s.bS1,s.bS11,s.bS2,s.bS22,s.bS12,sam_bn,pear_bn);

  Consts c;
  c.errBase = wgt[0]*sam_mm + wgt[1]*pear_mm + wgt[3]*sam_z + wgt[4]*pear_z
            + wgt[6]*sam_bn + wgt[7]*pear_bn;
  float dp = fmaf(s.psum - 128.f*s.pmin, smm_p, EPSF);
  c.fp = smm_p/dp;  c.Bp = s.pmin*c.fp;
  float dt = fmaf(s.tsum - 128.f*s.tmin, smm_t, EPSF);
  c.ft = smm_t/dt;  c.Bt = s.tmin*c.ft;
  c.fbp = 1.f/((s.bS1 - 128.f*s.bMp) + EPSF); c.Bbp = s.bMp*c.fbp;
  c.fbt = 1.f/((s.bS2 - 128.f*s.bMt) + EPSF); c.Bbt = s.bMt*c.fbt;
  c.sidW = (wgt[2]+wgt[5])*LN2F;
  c.bnW  = wgt[8]*LN2F;
  return c;
}

__global__ __launch_bounds__(256) void initWs(unsigned* __restrict__ wsu){
  int idx = blockIdx.x*256 + threadIdx.x;
  if (idx < WS_TOTAL) wsu[idx] = (idx == WS_MINKEY) ? 0xFFFFFFFFu : 0u;
}

// per-channel sums over (B,H,W) for both tensors.
// 256 threads/block, one 256KB plane per block; 64 float4 loads/thread issued
// in explicit batches of 8 (128B/lane in flight); 4 independent accum chains.
__global__ __launch_bounds__(256, 4) void bnSumKernel(const float* __restrict__ rec,
                                                      const float* __restrict__ tgt,
                                                      float* __restrict__ wsf){
  int blk = blockIdx.x;            // 0..1023: tensor(2) x b(4) x c(128)
  int tensor = blk >> 9;
  int rem = blk & 511;
  int c = rem & 127;
  int b = rem >> 7;
  const float4* src4 = (const float4*)((tensor==0 ? rec : tgt)
                        + ((size_t)(b*CCH + c))*HWSZ);
  int tid = threadIdx.x;

  float4 s0={0,0,0,0}, s1={0,0,0,0};   // sum chains
  float4 q0={0,0,0,0}, q1={0,0,0,0};   // sumsq chains

  for (int k=0;k<64;k+=8){
    float4 L[8];
    #pragma unroll
    for (int j=0;j<8;j++) L[j] = src4[tid + (k+j)*256];
    #pragma unroll
    for (int j=0;j<8;j+=2){
      float4 a=L[j], d=L[j+1];
      s0.x+=a.x; s0.y+=a.y; s0.z+=a.z; s0.w+=a.w;
      q0.x=fmaf(a.x,a.x,q0.x); q0.y=fmaf(a.y,a.y,q0.y);
      q0.z=fmaf(a.z,a.z,q0.z); q0.w=fmaf(a.w,a.w,q0.w);
      s1.x+=d.x; s1.y+=d.y; s1.z+=d.z; s1.w+=d.w;
      q1.x=fmaf(d.x,d.x,q1.x); q1.y=fmaf(d.y,d.y,q1.y);
      q1.z=fmaf(d.z,d.z,q1.z); q1.w=fmaf(d.w,d.w,q1.w);
    }
  }
  float s = (s0.x+s0.y)+(s0.z+s0.w) + (s1.x+s1.y)+(s1.z+s1.w);
  float q = (q0.x+q0.y)+(q0.z+q0.w) + (q1.x+q1.y)+(q1.z+q1.w);

  for (int off=1; off<64; off<<=1){ s += __shfl_xor(s,off); q += __shfl_xor(q,off); }
  __shared__ float ls[4], lq[4];
  int wid = tid >> 6;
  if ((tid & 63)==0){ ls[wid]=s; lq[wid]=q; }
  __syncthreads();
  if (tid==0){
    float S=ls[0]+ls[1]+ls[2]+ls[3];
    float Q=lq[0]+lq[1]+lq[2]+lq[3];
    atomicAdd(&wsf[tensor*256 + c], S);
    atomicAdd(&wsf[tensor*256 + 128 + c], Q);
  }
}

// bn inv-std and mean*inv-std per channel (both tensors) + softmax weights
__global__ __launch_bounds__(256) void finalizeKernel(const float* __restrict__ lw,
                                                      float* __restrict__ wsf){
  int tid = threadIdx.x;
  {
    int tensor = tid >> 7;
    int c = tid & 127;
    float S = wsf[tensor*256 + c];
    float Q = wsf[tensor*256 + 128 + c];
    const float N = 262144.f;
    float mean = S / N;
    float var = fmaxf((Q - S*S/N) / (N - 1.f), 0.f);
    float inv = 1.f/(sqrtf(var)+EPSF);
    wsf[WS_CST + c*4 + tensor*2 + 0] = inv;
    wsf[WS_CST + c*4 + tensor*2 + 1] = mean*inv;
  }
  if (tid==0){
    float m = -1e30f;
    for (int i=0;i<9;i++) m = fmaxf(m, lw[i]);
    float e[9], sum=0.f;
    for (int i=0;i<9;i++){ e[i]=expf(lw[i]-m); sum+=e[i]; }
    for (int i=0;i<9;i++) wsf[WS_WGT+i] = e[i]/sum;
  }
}

// main kernel: thread = 2 consecutive pixels (float2 loads -> 512B/wave-instr).
// Channel loop in batches of 8 with all 16 loads issued before consumption.
__global__ __launch_bounds__(256, 4) void mainKernel(const float* __restrict__ rec,
                                                     const float* __restrict__ tgt,
                                                     const float* __restrict__ wsf,
                                                     unsigned* __restrict__ wsu,
                                                     float* __restrict__ errMap){
  __shared__ float4 cst[128];    // (i_p, m_p*i_p, i_t, m_t*i_t)
  __shared__ float wgtS[12];
  __shared__ float rmn[4], rmx[4];
  int tid = threadIdx.x;
  if (tid < 128) cst[tid] = ((const float4*)(wsf + WS_CST))[tid];
  if (tid < 9)  wgtS[tid] = wsf[WS_WGT + tid];
  __syncthreads();

  int pix0 = blockIdx.x*512 + tid*2;
  int b = pix0 >> 16;
  unsigned hwb = (unsigned)(pix0 & (HWSZ-1)) * 4u;
  const char* pB = (const char*)(rec + ((size_t)b*CCH)*HWSZ) + hwb;
  const char* tB = (const char*)(tgt + ((size_t)b*CCH)*HWSZ) + hwb;

  float2 psum={0,0},psumsq={0,0},tsum={0,0},tsumsq={0,0},ptsum={0,0};
  float2 pmin={3.4e38f,3.4e38f},pmax={-3.4e38f,-3.4e38f};
  float2 tmin={3.4e38f,3.4e38f},tmax={-3.4e38f,-3.4e38f};
  float2 bS1={0,0},bS11={0,0},bS2={0,0},bS22={0,0},bS12={0,0};
  float2 bMp={3.4e38f,3.4e38f},bMt={3.4e38f,3.4e38f};

  for (int cb=0; cb<CCH; cb+=8){
    float2 P[8], T[8];
    #pragma unroll
    for (int j=0;j<8;j++){
      P[j] = *(const float2*)(pB + ((unsigned)(cb+j)<<18));
      T[j] = *(const float2*)(tB + ((unsigned)(cb+j)<<18));
    }
    #pragma unroll
    for (int j=0;j<8;j++){
      float4 k = cst[cb+j];
      float2 pv=P[j], tv=T[j];
      psum.x+=pv.x; psum.y+=pv.y;
      psumsq.x=fmaf(pv.x,pv.x,psumsq.x); psumsq.y=fmaf(pv.y,pv.y,psumsq.y);
      tsum.x+=tv.x; tsum.y+=tv.y;
      tsumsq.x=fmaf(tv.x,tv.x,tsumsq.x); tsumsq.y=fmaf(tv.y,tv.y,tsumsq.y);
      ptsum.x=fmaf(pv.x,tv.x,ptsum.x); ptsum.y=fmaf(pv.y,tv.y,ptsum.y);
      pmin.x=fminf(pmin.x,pv.x); pmin.y=fminf(pmin.y,pv.y);
      pmax.x=fmaxf(pmax.x,pv.x); pmax.y=fmaxf(pmax.y,pv.y);
      tmin.x=fminf(tmin.x,tv.x); tmin.y=fminf(tmin.y,tv.y);
      tmax.x=fmaxf(tmax.x,tv.x); tmax.y=fmaxf(tmax.y,tv.y);
      float bpx = fmaf(pv.x,k.x,-k.y), bpy = fmaf(pv.y,k.x,-k.y);
      float btx = fmaf(tv.x,k.z,-k.w), bty = fmaf(tv.y,k.z,-k.w);
      bS1.x+=bpx; bS1.y+=bpy;
      bS11.x=fmaf(bpx,bpx,bS11.x); bS11.y=fmaf(bpy,bpy,bS11.y);
      bS2.x+=btx; bS2.y+=bty;
      bS22.x=fmaf(btx,btx,bS22.x); bS22.y=fmaf(bty,bty,bS22.y);
      bS12.x=fmaf(bpx,btx,bS12.x); bS12.y=fmaf(bpy,bty,bS12.y);
      bMp.x=fminf(bMp.x,bpx); bMp.y=fminf(bMp.y,bpy);
      bMt.x=fminf(bMt.x,btx); bMt.y=fminf(bMt.y,bty);
    }
  }

  Stats sx = {psum.x,psumsq.x,tsum.x,tsumsq.x,ptsum.x,pmin.x,pmax.x,tmin.x,tmax.x,
              bS1.x,bS11.x,bS2.x,bS22.x,bS12.x,bMp.x,bMt.x};
  Stats sy = {psum.y,psumsq.y,tsum.y,tsumsq.y,ptsum.y,pmin.y,pmax.y,tmin.y,tmax.y,
              bS1.y,bS11.y,bS2.y,bS22.y,bS12.y,bMp.y,bMt.y};
  Consts cx = pixEpilogue(sx, wgtS);
  Consts cy = pixEpilogue(sy, wgtS);

  float2 sid_mm={0,0}, sid_bn={0,0};
  for (int cb=0; cb<CCH; cb+=8){
    float2 P[8], T[8];
    #pragma unroll
    for (int j=0;j<8;j++){
      P[j] = *(const float2*)(pB + ((unsigned)(cb+j)<<18));
      T[j] = *(const float2*)(tB + ((unsigned)(cb+j)<<18));
    }
    #pragma unroll
    for (int j=0;j<8;j++){
      float4 k = cst[cb+j];
      float2 pv=P[j], tv=T[j];
      float ppx = fmaxf(fmaf(pv.x,cx.fp,-cx.Bp), EPSF);
      float tpx = fmaxf(fmaf(tv.x,cx.ft,-cx.Bt), EPSF);
      sid_mm.x = fmaf(ppx-tpx, __log2f(ppx)-__log2f(tpx), sid_mm.x);
      float ppy = fmaxf(fmaf(pv.y,cy.fp,-cy.Bp), EPSF);
      float tpy = fmaxf(fmaf(tv.y,cy.ft,-cy.Bt), EPSF);
      sid_mm.y = fmaf(ppy-tpy, __log2f(ppy)-__log2f(tpy), sid_mm.y);
      float bpx = fmaf(pv.x,k.x,-k.y), bpy = fmaf(pv.y,k.x,-k.y);
      float btx = fmaf(tv.x,k.z,-k.w), bty = fmaf(tv.y,k.z,-k.w);
      float qpx = fmaxf(fmaf(bpx,cx.fbp,-cx.Bbp), EPSF);
      float qtx = fmaxf(fmaf(btx,cx.fbt,-cx.Bbt), EPSF);
      sid_bn.x = fmaf(qpx-qtx, __log2f(qpx)-__log2f(qtx), sid_bn.x);
      float qpy = fmaf(bpy,cy.fbp,-cy.Bbp);  qpy = fmaxf(qpy, EPSF);
      float qty = fmaf(bty,cy.fbt,-cy.Bbt);  qty = fmaxf(qty, EPSF);
      sid_bn.y = fmaf(qpy-qty, __log2f(qpy)-__log2f(qty), sid_bn.y);
    }
  }

  float errx = cx.errBase + cx.sidW*sid_mm.x + cx.bnW*sid_bn.x;
  float erry = cy.errBase + cy.sidW*sid_mm.y + cy.bnW*sid_bn.y;
  errMap[pix0]   = errx;
  errMap[pix0+1] = erry;

  float emin = fminf(errx,erry), emax = fmaxf(errx,erry);
  #pragma unroll
  for (int off=1; off<64; off<<=1){
    emin = fminf(emin, __shfl_xor(emin,off));
    emax = fmaxf(emax, __shfl_xor(emax,off));
  }
  int w = tid>>6;
  if ((tid&63)==0){ rmn[w]=emin; rmx[w]=emax; }
  __syncthreads();
  if (tid==0){
    emin = fminf(fminf(rmn[0],rmn[1]),fminf(rmn[2],rmn[3]));
    emax = fmaxf(fmaxf(rmx[0],rmx[1]),fmaxf(rmx[2],rmx[3]));
    atomicMin(&wsu[WS_MINKEY], fkey(emin));
    atomicMax(&wsu[WS_MAXKEY], fkey(emax));
  }
}

__global__ __launch_bounds__(256) void hist1Kernel(const float* __restrict__ err,
                                                   unsigned* __restrict__ wsu){
  __shared__ unsigned h[4096];
  int tid = threadIdx.x;
  for (int i=tid;i<4096;i+=256) h[i]=0u;
  __syncthreads();
  float lo = funkey(wsu[WS_MINKEY]);
  float hi = funkey(wsu[WS_MAXKEY]);
  float invw = 4096.f / fmaxf(hi-lo, 1e-30f);
  int base = blockIdx.x*2048 + tid;
  for (int j=0;j<8;j++){
    float v = err[base + j*256];
    int idx = (int)fminf(fmaxf((v-lo)*invw, 0.f), 4095.f);
    atomicAdd(&h[idx], 1u);
  }
  __syncthreads();
  for (int i=tid;i<4096;i+=256){ unsigned c=h[i]; if (c) atomicAdd(&wsu[WS_H1+i], c); }
}

__global__ __launch_bounds__(256) void scan1Kernel(float* __restrict__ wsf,
                                                   unsigned* __restrict__ wsu){
  __shared__ unsigned counts[4096];
  __shared__ unsigned s[256];
  int tid = threadIdx.x;
  for (int i=tid;i<4096;i+=256) counts[i]=wsu[WS_H1+i];
  __syncthreads();
  unsigned part=0;
  for (int j=0;j<16;j++) part += counts[tid*16+j];
  s[tid]=part; __syncthreads();
  for (int off=1; off<256; off<<=1){
    unsigned v = (tid+off<256)? s[tid+off] : 0u;
    __syncthreads();
    s[tid] += v;
    __syncthreads();
  }
  float lo = funkey(wsu[WS_MINKEY]);
  float hi = funkey(wsu[WS_MAXKEY]);
  float w1 = fmaxf(hi-lo, 1e-30f) * (1.f/4096.f);
  unsigned cum = (tid<255)? s[tid+1] : 0u;
  for (int j=15;j>=0;j--){
    int bin = tid*16+j;
    unsigned cn = cum + counts[bin];
    if (cum < (unsigned)KTOP && cn >= (unsigned)KTOP){
      wsu[WS_BSTAR] = (unsigned)bin;
      wsu[WS_CNTAB] = cum;
      wsu[WS_K2]    = (unsigned)KTOP - cum;
      wsf[WS_LO2]   = lo + (float)bin*w1;
      wsf[WS_W2]    = w1*(1.f/4096.f);
    }
    cum = cn;
  }
}

__global__ __launch_bounds__(256) void hist2Kernel(const float* __restrict__ err,
                                                   float* __restrict__ wsf,
                                                   unsigned* __restrict__ wsu){
  __shared__ unsigned h2[4096];
  __shared__ float s2[4096];
  __shared__ float ls[4];
  int tid = threadIdx.x;
  for (int i=tid;i<4096;i+=256){ h2[i]=0u; s2[i]=0.f; }
  __syncthreads();
  float lo = funkey(wsu[WS_MINKEY]);
  float hi = funkey(wsu[WS_MAXKEY]);
  float invw = 4096.f / fmaxf(hi-lo, 1e-30f);
  int bstar = (int)wsu[WS_BSTAR];
  float lo2 = wsf[WS_LO2];
  float w2  = wsf[WS_W2];
  float invw2 = 1.f / w2;
  float mySum = 0.f;
  int base = blockIdx.x*2048 + tid;
  for (int j=0;j<8;j++){
    float v = err[base + j*256];
    int idx = (int)fminf(fmaxf((v-lo)*invw, 0.f), 4095.f);
    if (idx > bstar){
      mySum += v;
    } else if (idx == bstar){
      int i2 = (int)fminf(fmaxf((v-lo2)*invw2, 0.f), 4095.f);
      atomicAdd(&h2[i2], 1u);
      atomicAdd(&s2[i2], v);
    }
  }
  for (int off=1; off<64; off<<=1) mySum += __shfl_xor(mySum, off);
  if ((tid&63)==0) ls[tid>>6] = mySum;
  __syncthreads();
  if (tid==0) atomicAdd(&wsf[WS_SUMAB], ls[0]+ls[1]+ls[2]+ls[3]);
  for (int i=tid;i<4096;i+=256){
    unsigned c = h2[i]; if (c) atomicAdd(&wsu[WS_H2C+i], c);
    float sv = s2[i];   if (sv != 0.f) atomicAdd(&wsf[WS_H2S+i], sv);
  }
}

__global__ __launch_bounds__(256) void scan2Kernel(float* __restrict__ wsf,
                                                   unsigned* __restrict__ wsu,
                                                   float* __restrict__ out){
  __shared__ unsigned cnt[4096];
  __shared__ float sm[4096];
  __shared__ unsigned sC[256];
  __shared__ float sS[256];
  int tid = threadIdx.x;
  for (int i=tid;i<4096;i+=256){ cnt[i]=wsu[WS_H2C+i]; sm[i]=wsf[WS_H2S+i]; }
  __syncthreads();
  unsigned pc=0; float ps=0.f;
  for (int j=0;j<16;j++){ pc+=cnt[tid*16+j]; ps+=sm[tid*16+j]; }
  sC[tid]=pc; sS[tid]=ps; __syncthreads();
  for (int off=1; off<256; off<<=1){
    unsigned vc = (tid+off<256)? sC[tid+off] : 0u;
    float vs    = (tid+off<256)? sS[tid+off] : 0.f;
    __syncthreads();
    sC[tid] += vc; sS[tid] += vs;
    __syncthreads();
  }
  unsigned k2 = wsu[WS_K2];
  float lo2 = wsf[WS_LO2], w2 = wsf[WS_W2];
  unsigned cum = (tid<255)? sC[tid+1] : 0u;
  float cums   = (tid<255)? sS[tid+1] : 0.f;
  for (int j=15;j>=0;j--){
    int bin = tid*16+j;
    unsigned cn = cum + cnt[bin];
    float sn = cums + sm[bin];
    if (cum < k2 && cn >= k2){
      float val = lo2 + ((float)bin + 0.5f)*w2;
      float total = wsf[WS_SUMAB] + cums + (float)(k2 - cum)*val;
      out[0] = total / (float)KTOP;
    }
    cum = cn; cums = sn;
  }
}

extern "C" void kernel_launch(void* const* d_in, const int* in_sizes, int n_in,
                              void* d_out, int out_size, void* d_ws, size_t ws_size,
                              hipStream_t stream){
  const float* rec = (const float*)d_in[0];
  const float* tgt = (const float*)d_in[1];
  const float* lw  = (const float*)d_in[2];
  float* out = (float*)d_out;
  float* wsf = (float*)d_ws;
  unsigned* wsu = (unsigned*)d_ws;

  hipLaunchKernelGGL(initWs, dim3((WS_TOTAL+255)/256), dim3(256), 0, stream, wsu);
  hipLaunchKernelGGL(bnSumKernel, dim3(1024), dim3(256), 0, stream, rec, tgt, wsf);
  hipLaunchKernelGGL(finalizeKernel, dim3(1), dim3(256), 0, stream, lw, wsf);
  hipLaunchKernelGGL(mainKernel, dim3(NPIX/512), dim3(256), 0, stream, rec, tgt, wsf, wsu, out+1);
  hipLaunchKernelGGL(hist1Kernel, dim3(128), dim3(256), 0, stream, out+1, wsu);
  hipLaunchKernelGGL(scan1Kernel, dim3(1), dim3(256), 0, stream, wsf, wsu);
  hipLaunchKernelGGL(hist2Kernel, dim3(128), dim3(256), 0, stream, out+1, wsf, wsu);
  hipLaunchKernelGGL(scan2Kernel, dim3(1), dim3(256), 0, stream, wsf, wsu, out);
}